// Round 1
// baseline (6695.760 us; speedup 1.0000x reference)
//
#include <hip/hip_runtime.h>
#include <cstddef>
#include <cstdint>

#define NNODE 20000
#define NEDGE 320000
#define NFEDGE 500000
#define DIM 256
#define NHEAD 8
#define NGRAPH 100
// 1/sqrt(32)
#define INV_SCALE 0.17677669529663687f

// ---------------------------------------------------------------------------
// Generic fp32 GEMM: C = A(MxK) @ W(KxNn) + bias (+ res). 64x64 tile, BK=16,
// 256 threads, 4x4 microtile per thread.
// ---------------------------------------------------------------------------
__global__ __launch_bounds__(256)
void gemm_kernel(const float* __restrict__ A, const float* __restrict__ W,
                 const float* __restrict__ bias, const float* __restrict__ res,
                 float* __restrict__ C, int M, int K, int Nn)
{
    __shared__ float As[16][64];
    __shared__ float Ws[16][64];
    const int tid = threadIdx.x;
    const int tx = tid & 15;         // N direction (x4)
    const int ty = tid >> 4;         // M direction (x4)
    const int m0 = blockIdx.y * 64;
    const int n0 = blockIdx.x * 64;

    float c[4][4] = {};

    for (int k0 = 0; k0 < K; k0 += 16) {
        // A tile: 64 rows x 16 k, stored transposed As[k][m]
        {
            int r  = tid >> 2;             // 0..63 row in tile
            int k4 = (tid & 3) * 4;        // 0,4,8,12
            int row = m0 + r; if (row >= M) row = M - 1;   // clamp (stores guarded)
            const float4 v = *(const float4*)(A + (size_t)row * K + k0 + k4);
            As[k4 + 0][r] = v.x; As[k4 + 1][r] = v.y;
            As[k4 + 2][r] = v.z; As[k4 + 3][r] = v.w;
        }
        // W tile: 16 k x 64 n
        {
            int kr = tid >> 4;             // 0..15
            int n4 = (tid & 15) * 4;
            *(float4*)&Ws[kr][n4] = *(const float4*)(W + (size_t)(k0 + kr) * Nn + n0 + n4);
        }
        __syncthreads();
        #pragma unroll
        for (int kk = 0; kk < 16; ++kk) {
            float a_[4], w_[4];
            *(float4*)a_ = *(const float4*)&As[kk][ty * 4];
            *(float4*)w_ = *(const float4*)&Ws[kk][tx * 4];
            #pragma unroll
            for (int i = 0; i < 4; ++i)
                #pragma unroll
                for (int j = 0; j < 4; ++j)
                    c[i][j] += a_[i] * w_[j];
        }
        __syncthreads();
    }

    float bv[4];
    *(float4*)bv = *(const float4*)(bias + n0 + tx * 4);
    #pragma unroll
    for (int i = 0; i < 4; ++i) {
        int row = m0 + ty * 4 + i;
        if (row >= M) continue;
        size_t off = (size_t)row * Nn + n0 + tx * 4;
        float o[4];
        #pragma unroll
        for (int j = 0; j < 4; ++j) o[j] = c[i][j] + bv[j];
        if (res) {
            float rv[4];
            *(float4*)rv = *(const float4*)(res + off);
            #pragma unroll
            for (int j = 0; j < 4; ++j) o[j] += rv[j];
        }
        *(float4*)(C + off) = *(float4*)o;
    }
}

// ---------------------------------------------------------------------------
// Fused FFN: out = relu(X@W1 + b1) @ W2 + b2 + res.  X: Mx256, W1: 256x512,
// W2: 512x256. 16-row tile per block, 256 threads, mid kept in LDS.
// ---------------------------------------------------------------------------
__global__ __launch_bounds__(256)
void ffn_kernel(const float* __restrict__ X, const float* __restrict__ W1,
                const float* __restrict__ b1, const float* __restrict__ W2,
                const float* __restrict__ b2, const float* __restrict__ res,
                float* __restrict__ out, int M)
{
    __shared__ float Xs[16][260];    // +4 pad, rows stay 16B aligned
    __shared__ float Mid[16][516];
    const int t = threadIdx.x;
    const int m0 = blockIdx.x * 16;

    // load X tile
    {
        int r = t >> 4, c0 = (t & 15) * 16;
        int row = m0 + r; if (row >= M) row = M - 1;
        const float* src = X + (size_t)row * 256 + c0;
        #pragma unroll
        for (int j = 0; j < 4; ++j)
            *(float4*)&Xs[r][c0 + 4 * j] = *(const float4*)(src + 4 * j);
    }
    __syncthreads();

    // phase 1: mid columns j0=t, j1=t+256 for all 16 rows
    float acc0[16] = {}, acc1[16] = {};
    const float* w1p = W1 + t;
    for (int k4 = 0; k4 < 256; k4 += 4) {
        float w0[4], w1[4];
        #pragma unroll
        for (int i = 0; i < 4; ++i) {
            w0[i] = w1p[(size_t)(k4 + i) * 512];
            w1[i] = w1p[(size_t)(k4 + i) * 512 + 256];
        }
        #pragma unroll
        for (int r = 0; r < 16; ++r) {
            float xv[4];
            *(float4*)xv = *(const float4*)&Xs[r][k4];
            acc0[r] += xv[0] * w0[0] + xv[1] * w0[1] + xv[2] * w0[2] + xv[3] * w0[3];
            acc1[r] += xv[0] * w1[0] + xv[1] * w1[1] + xv[2] * w1[2] + xv[3] * w1[3];
        }
    }
    {
        float bb0 = b1[t], bb1 = b1[t + 256];
        #pragma unroll
        for (int r = 0; r < 16; ++r) {
            Mid[r][t]       = fmaxf(acc0[r] + bb0, 0.f);
            Mid[r][t + 256] = fmaxf(acc1[r] + bb1, 0.f);
        }
    }
    __syncthreads();

    // phase 2: out(16x256) = Mid(16x512)@W2.  8 rows x 2 cols per thread.
    const int rh = (t >> 7) * 8;      // 0 or 8
    const int j0 = t & 127;
    const int j1 = j0 + 128;
    float d0[8] = {}, d1[8] = {};
    for (int k4 = 0; k4 < 512; k4 += 4) {
        float wa[4], wb[4];
        #pragma unroll
        for (int i = 0; i < 4; ++i) {
            wa[i] = W2[(size_t)(k4 + i) * 256 + j0];
            wb[i] = W2[(size_t)(k4 + i) * 256 + j1];
        }
        #pragma unroll
        for (int r = 0; r < 8; ++r) {
            float mv[4];
            *(float4*)mv = *(const float4*)&Mid[rh + r][k4];
            d0[r] += mv[0] * wa[0] + mv[1] * wa[1] + mv[2] * wa[2] + mv[3] * wa[3];
            d1[r] += mv[0] * wb[0] + mv[1] * wb[1] + mv[2] * wb[2] + mv[3] * wb[3];
        }
    }
    float bb0 = b2[j0], bb1 = b2[j1];
    #pragma unroll
    for (int r = 0; r < 8; ++r) {
        int row = m0 + rh + r;
        if (row >= M) continue;
        size_t i0 = (size_t)row * 256 + j0;
        size_t i1 = (size_t)row * 256 + j1;
        out[i0] = d0[r] + bb0 + res[i0];
        out[i1] = d1[r] + bb1 + res[i1];
    }
}

// ---------------------------------------------------------------------------
// Sparse-graph edge kernel. One block = one edge, 256 threads = 8 heads x 32.
// score = Kh[src]*Qh[dst]/SCALE*proj_e (written back as e_out, in place),
// s = exp(clip(sum_d score)), atomic scatter of Vh[src]*s and s.
// ---------------------------------------------------------------------------
__global__ __launch_bounds__(256)
void sedge_kernel(const float* __restrict__ Kh, const float* __restrict__ Qh,
                  const float* __restrict__ Vh, float* __restrict__ pe,
                  const int* __restrict__ src, const int* __restrict__ dst,
                  float* __restrict__ wV, float* __restrict__ z)
{
    const int e = blockIdx.x;
    const int t = threadIdx.x;
    const int s_ = src[e], d_ = dst[e];
    const size_t eb = (size_t)e * 256;
    float k = Kh[(size_t)s_ * 256 + t];
    float q = Qh[(size_t)d_ * 256 + t];
    float p = pe[eb + t];
    float score = k * q * INV_SCALE * p;
    pe[eb + t] = score;                      // e_out (pre-exp), in place
    float red = score;
    red += __shfl_down(red, 16, 32);
    red += __shfl_down(red, 8, 32);
    red += __shfl_down(red, 4, 32);
    red += __shfl_down(red, 2, 32);
    red += __shfl_down(red, 1, 32);
    float ssum = __shfl(red, 0, 32);
    float sexp = expf(fminf(fmaxf(ssum, -5.f), 5.f));
    float v = Vh[(size_t)s_ * 256 + t];
    atomicAdd(&wV[(size_t)d_ * 256 + t], v * sexp);
    if ((t & 31) == 0) atomicAdd(&z[d_ * NHEAD + (t >> 5)], sexp);
}

// ---------------------------------------------------------------------------
// Full-graph edge kernel. sc = dot(Kh[fsrc],Qh[fdst])/SCALE per head;
// sf = exp(clip(sc + rel)* adj2); atomic scatter.
// ---------------------------------------------------------------------------
__global__ __launch_bounds__(256)
void fedge_kernel(const float* __restrict__ Kh, const float* __restrict__ Qh,
                  const float* __restrict__ Vh,
                  const int* __restrict__ fsrc, const int* __restrict__ fdst,
                  const float* __restrict__ adj2, const float* __restrict__ rel,
                  float* __restrict__ wVf, float* __restrict__ zf)
{
    const int e = blockIdx.x;
    const int t = threadIdx.x;
    const int h = t >> 5;
    const int s_ = fsrc[e], d_ = fdst[e];
    float prod = Kh[(size_t)s_ * 256 + t] * Qh[(size_t)d_ * 256 + t];
    float red = prod;
    red += __shfl_down(red, 16, 32);
    red += __shfl_down(red, 8, 32);
    red += __shfl_down(red, 4, 32);
    red += __shfl_down(red, 2, 32);
    red += __shfl_down(red, 1, 32);
    float sc = __shfl(red, 0, 32) * INV_SCALE;
    float sf = expf(fminf(fmaxf(sc + rel[(size_t)e * NHEAD + h], -5.f), 5.f) * adj2[e]);
    atomicAdd(&wVf[(size_t)d_ * 256 + t], Vh[(size_t)s_ * 256 + t] * sf);
    if ((t & 31) == 0) atomicAdd(&zf[d_ * NHEAD + h], sf);
}

// h_attn = wV/(z+eps) + wVf/(zf+eps)
__global__ __launch_bounds__(256)
void hattn_kernel(const float* __restrict__ wV, const float* __restrict__ z,
                  const float* __restrict__ wVf, const float* __restrict__ zf,
                  float* __restrict__ ha)
{
    size_t i = (size_t)blockIdx.x * 256 + threadIdx.x;
    int n = (int)(i >> 8);
    int h = (int)((i >> 5) & 7);
    ha[i] = wV[i] / (z[n * NHEAD + h] + 1e-6f) + wVf[i] / (zf[n * NHEAD + h] + 1e-6f);
}

// graph boundary detection on sorted graph_ids -> gstart[0..NG] (gstart[NG]=N)
__global__ void bounds_kernel(const int* __restrict__ gid, int* __restrict__ gstart,
                              int n_, int ng)
{
    int n = blockIdx.x * 256 + threadIdx.x;
    if (n >= n_) return;
    int cur = gid[n];
    int prev = (n == 0) ? -1 : gid[n - 1];
    for (int g = prev + 1; g <= cur; ++g) gstart[g] = n;
    if (n == n_ - 1)
        for (int g = cur + 1; g <= ng; ++g) gstart[g] = n_;
}

// GraphNorm in place: one block per graph, thread d = feature.
__global__ __launch_bounds__(256)
void gn_kernel(float* __restrict__ x, const float* __restrict__ alpha,
               const float* __restrict__ gamma, const float* __restrict__ beta,
               const int* __restrict__ gstart)
{
    const int g = blockIdx.x;
    const int d = threadIdx.x;
    const int s = gstart[g], en = gstart[g + 1];
    if (s >= en) return;
    const float cnt = (float)(en - s);
    float sum = 0.f;
    for (int n = s; n < en; ++n) sum += x[(size_t)n * 256 + d];
    const float mean = sum / cnt;
    const float am = alpha[d] * mean;
    float sum2 = 0.f;
    for (int n = s; n < en; ++n) {
        float v = x[(size_t)n * 256 + d] - am;
        sum2 += v * v;
    }
    const float inv = 1.0f / sqrtf(sum2 / cnt + 1e-6f);
    const float gm = gamma[d], bt = beta[d];
    for (int n = s; n < en; ++n) {
        float v = x[(size_t)n * 256 + d] - am;
        x[(size_t)n * 256 + d] = gm * v * inv + bt;
    }
}

// LayerNorm over D=256, in place. One 64-lane wave per row, 4 rows per block.
__global__ __launch_bounds__(256)
void ln_kernel(float* __restrict__ x, const float* __restrict__ g,
               const float* __restrict__ b, int M)
{
    int row = blockIdx.x * 4 + (threadIdx.x >> 6);
    int lane = threadIdx.x & 63;
    if (row >= M) return;
    float* xr = x + (size_t)row * 256;
    float v0 = xr[lane], v1 = xr[lane + 64], v2 = xr[lane + 128], v3 = xr[lane + 192];
    float s = v0 + v1 + v2 + v3;
    for (int off = 32; off; off >>= 1) s += __shfl_down(s, off, 64);
    float mu = __shfl(s, 0, 64) * (1.0f / 256.0f);
    float d0 = v0 - mu, d1 = v1 - mu, d2 = v2 - mu, d3 = v3 - mu;
    float q = d0 * d0 + d1 * d1 + d2 * d2 + d3 * d3;
    for (int off = 32; off; off >>= 1) q += __shfl_down(q, off, 64);
    float var = __shfl(q, 0, 64) * (1.0f / 256.0f);
    float inv = 1.0f / sqrtf(var + 1e-5f);
    xr[lane]       = d0 * inv * g[lane]       + b[lane];
    xr[lane + 64]  = d1 * inv * g[lane + 64]  + b[lane + 64];
    xr[lane + 128] = d2 * inv * g[lane + 128] + b[lane + 128];
    xr[lane + 192] = d3 * inv * g[lane + 192] + b[lane + 192];
}

// ---------------------------------------------------------------------------
extern "C" void kernel_launch(void* const* d_in, const int* in_sizes, int n_in,
                              void* d_out, int out_size, void* d_ws, size_t ws_size,
                              hipStream_t stream)
{
    const float* h        = (const float*)d_in[0];
    const float* e        = (const float*)d_in[1];
    const int*   src      = (const int*)d_in[2];
    const int*   dst      = (const int*)d_in[3];
    const int*   fsrc     = (const int*)d_in[4];
    const int*   fdst     = (const int*)d_in[5];
    const float* adj2     = (const float*)d_in[6];
    const float* rel      = (const float*)d_in[7];
    const int*   gids     = (const int*)d_in[8];
    const float* Qw  = (const float*)d_in[9];
    const float* Kw  = (const float*)d_in[10];
    const float* Vw  = (const float*)d_in[11];
    const float* Pw  = (const float*)d_in[12];
    const float* Ohw = (const float*)d_in[13];
    const float* Oew = (const float*)d_in[14];
    const float* Qb  = (const float*)d_in[15];
    const float* Kb  = (const float*)d_in[16];
    const float* Vb  = (const float*)d_in[17];
    const float* Pb  = (const float*)d_in[18];
    const float* Ohb = (const float*)d_in[19];
    const float* Oeb = (const float*)d_in[20];
    const float* f1hw = (const float*)d_in[21];
    const float* f1hb = (const float*)d_in[22];
    const float* f2hw = (const float*)d_in[23];
    const float* f2hb = (const float*)d_in[24];
    const float* f1ew = (const float*)d_in[25];
    const float* f1eb = (const float*)d_in[26];
    const float* f2ew = (const float*)d_in[27];
    const float* f2eb = (const float*)d_in[28];
    const float* gn1_alpha = (const float*)d_in[29];
    const float* gn1_gamma = (const float*)d_in[30];
    const float* gn2_alpha = (const float*)d_in[31];
    const float* gn2_gamma = (const float*)d_in[32];
    const float* ln1e_g = (const float*)d_in[33];
    const float* ln2e_g = (const float*)d_in[34];
    const float* gn1_beta = (const float*)d_in[35];
    const float* gn2_beta = (const float*)d_in[36];
    const float* ln1e_b = (const float*)d_in[37];
    const float* ln2e_b = (const float*)d_in[38];

    const size_t ND = (size_t)NNODE * DIM;   // 5,120,000
    const size_t ED = (size_t)NEDGE * DIM;   // 81,920,000

    float* wsf    = (float*)d_ws;
    float* Qh     = wsf;
    float* Kh     = Qh + ND;
    float* Vh     = Kh + ND;
    float* wV     = Vh + ND;
    float* wVf    = wV + ND;
    float* z      = wVf + ND;
    float* zf     = z + (size_t)NNODE * NHEAD;
    float* h_attn = zf + (size_t)NNODE * NHEAD;
    float* h2     = h_attn + ND;
    float* e2     = h2 + ND;
    int*   gstart = (int*)(e2 + ED);         // NGRAPH+1 ints

    float* out_h = (float*)d_out;            // final h2  [N,256]
    float* out_e = out_h + ND;               // proj_e -> e_out -> final e2 [E,256]

    // zero the scatter accumulators (wV, wVf, z, zf are contiguous)
    hipMemsetAsync(wV, 0, (2 * ND + 2 * (size_t)NNODE * NHEAD) * sizeof(float), stream);

    dim3 blk(256);
    // QKV projections
    gemm_kernel<<<dim3(4, 313), blk, 0, stream>>>(h, Qw, Qb, nullptr, Qh, NNODE, 256, 256);
    gemm_kernel<<<dim3(4, 313), blk, 0, stream>>>(h, Kw, Kb, nullptr, Kh, NNODE, 256, 256);
    gemm_kernel<<<dim3(4, 313), blk, 0, stream>>>(h, Vw, Vb, nullptr, Vh, NNODE, 256, 256);
    // proj_e into the e-output region (overwritten as e_out in sedge_kernel)
    gemm_kernel<<<dim3(4, 5000), blk, 0, stream>>>(e, Pw, Pb, nullptr, out_e, NEDGE, 256, 256);

    bounds_kernel<<<(NNODE + 255) / 256, blk, 0, stream>>>(gids, gstart, NNODE, NGRAPH);

    sedge_kernel<<<NEDGE, blk, 0, stream>>>(Kh, Qh, Vh, out_e, src, dst, wV, z);
    fedge_kernel<<<NFEDGE, blk, 0, stream>>>(Kh, Qh, Vh, fsrc, fdst, adj2, rel, wVf, zf);

    hattn_kernel<<<(int)(ND / 256), blk, 0, stream>>>(wV, z, wVf, zf, h_attn);

    // output projections with residual
    gemm_kernel<<<dim3(4, 313), blk, 0, stream>>>(h_attn, Ohw, Ohb, h, h2, NNODE, 256, 256);
    gemm_kernel<<<dim3(4, 5000), blk, 0, stream>>>(out_e, Oew, Oeb, e, e2, NEDGE, 256, 256);

    // norms (in place)
    gn_kernel<<<NGRAPH, blk, 0, stream>>>(h2, gn1_alpha, gn1_gamma, gn1_beta, gstart);
    ln_kernel<<<NEDGE / 4, blk, 0, stream>>>(e2, ln1e_g, ln1e_b, NEDGE);

    // fused FFNs (residual = normed input), write into d_out
    ffn_kernel<<<NNODE / 16, blk, 0, stream>>>(h2, f1hw, f1hb, f2hw, f2hb, h2, out_h, NNODE);
    ffn_kernel<<<NEDGE / 16, blk, 0, stream>>>(e2, f1ew, f1eb, f2ew, f2eb, e2, out_e, NEDGE);

    // final norms in place on d_out
    gn_kernel<<<NGRAPH, blk, 0, stream>>>(out_h, gn2_alpha, gn2_gamma, gn2_beta, gstart);
    ln_kernel<<<NEDGE / 4, blk, 0, stream>>>(out_e, ln2e_g, ln2e_b, NEDGE);
}